// Round 1
// baseline (272.384 us; speedup 1.0000x reference)
//
#include <hip/hip_runtime.h>

// One thread per batch row. Row-major x[B][12]; 3x float4 loads per row
// (48 B stride, 16 B/lane — every cache line fully consumed across the 3
// load instructions). Weights are wave-uniform -> scalar loads.
__global__ __launch_bounds__(256) void QGN_30219389895238_kernel(
    const float* __restrict__ x,   // [n, 12]
    const float* __restrict__ w,   // [24]
    float* __restrict__ out,       // [n]
    int n) {
  int i = blockIdx.x * blockDim.x + threadIdx.x;
  if (i >= n) return;

  const float4* __restrict__ xr = reinterpret_cast<const float4*>(x + (size_t)i * 12);
  float4 r0 = xr[0];
  float4 r1 = xr[1];
  float4 r2 = xr[2];
  float xv[12] = {r0.x, r0.y, r0.z, r0.w,
                  r1.x, r1.y, r1.z, r1.w,
                  r2.x, r2.y, r2.z, r2.w};

  // state |0> : s0 = 1+0i, s1 = 0+0i
  float s0r = 1.0f, s0i = 0.0f, s1r = 0.0f, s1i = 0.0f;

#pragma unroll
  for (int g = 0; g < 4; ++g) {
    float phi   = w[6 * g + 0] + xv[3 * g + 0] * w[6 * g + 1];
    float theta = w[6 * g + 2] + xv[3 * g + 1] * w[6 * g + 3];
    float omega = w[6 * g + 4] + xv[3 * g + 2] * w[6 * g + 5];

    float s, c;
    __sincosf(theta * 0.5f, &s, &c);       // c = cos(theta/2), s = sin(theta/2)
    float a = 0.5f * (phi + omega);
    float b = 0.5f * (phi - omega);
    float sa, ca, sb, cb;
    __sincosf(a, &sa, &ca);                // ea = e^{-ia} = (ca, -sa)
    __sincosf(b, &sb, &cb);                // eb = e^{+ib} = (cb, +sb)

    // m00 = ea*c        = ( ca*c, -sa*c)
    // m01 = -eb*s       = (-cb*s, -sb*s)
    // m10 = conj(eb)*s  = ( cb*s, -sb*s)
    // m11 = conj(ea)*c  = ( ca*c,  sa*c)
    float m00r =  ca * c, m00i = -sa * c;
    float m01r = -cb * s, m01i = -sb * s;
    float m10r =  cb * s, m10i = -sb * s;
    float m11r =  ca * c, m11i =  sa * c;

    float n0r = m00r * s0r - m00i * s0i + m01r * s1r - m01i * s1i;
    float n0i = m00r * s0i + m00i * s0r + m01r * s1i + m01i * s1r;
    float n1r = m10r * s0r - m10i * s0i + m11r * s1r - m11i * s1i;
    float n1i = m10r * s0i + m10i * s0r + m11r * s1i + m11i * s1r;
    s0r = n0r; s0i = n0i; s1r = n1r; s1i = n1i;
  }

  out[i] = s0r * s0r + s0i * s0i;
}

extern "C" void kernel_launch(void* const* d_in, const int* in_sizes, int n_in,
                              void* d_out, int out_size, void* d_ws, size_t ws_size,
                              hipStream_t stream) {
  const float* x = (const float*)d_in[0];  // [B,12] fp32
  const float* w = (const float*)d_in[1];  // [24]   fp32
  float* out = (float*)d_out;              // [B]    fp32
  int n = in_sizes[0] / 12;
  int block = 256;
  int grid = (n + block - 1) / block;
  QGN_30219389895238_kernel<<<grid, block, 0, stream>>>(x, w, out, n);
}